// Round 2
// baseline (449.926 us; speedup 1.0000x reference)
//
#include <hip/hip_runtime.h>

#define DIM 1024
#define NH 16
#define NKV 4
#define HD 64
#define INTER 2688
#define BB 2
#define NN 2048
#define MM (BB*NN)

typedef __attribute__((ext_vector_type(4))) float f32x4;
typedef __attribute__((ext_vector_type(8))) short short8;

__device__ __forceinline__ unsigned short f2bf(float f) {
  union { float f; unsigned u; } v; v.f = f;
  unsigned r = v.u + 0x7fffu + ((v.u >> 16) & 1u);
  return (unsigned short)(r >> 16);
}

// async global->LDS, 16B per lane; LDS dest is wave-uniform base + lane*16
__device__ __forceinline__ void glds16(const unsigned short* g, unsigned short* l) {
  __builtin_amdgcn_global_load_lds(
      (const __attribute__((address_space(1))) void*)g,
      (__attribute__((address_space(3))) void*)l, 16, 0, 0);
}

// ---------------- transpose fp32 [K][Nc] -> bf16 [Nc][K] ----------------
__global__ void transpose_k(const float* __restrict__ W, unsigned short* __restrict__ Wt,
                            int K, int Nc) {
  __shared__ float tile[32][33];
  int n0 = blockIdx.x * 32, k0 = blockIdx.y * 32;
  int tx = threadIdx.x & 31, ty = threadIdx.x >> 5;
#pragma unroll
  for (int i = 0; i < 32; i += 8)
    tile[ty + i][tx] = W[(size_t)(k0 + ty + i) * Nc + n0 + tx];
  __syncthreads();
#pragma unroll
  for (int i = 0; i < 32; i += 8)
    Wt[(size_t)(n0 + ty + i) * K + k0 + tx] = f2bf(tile[tx][ty + i]);
}

// ---------------- RMSNorm: fp32 [rows][1024] -> bf16 ----------------
__global__ void rmsnorm_k(const float* __restrict__ x, const float* __restrict__ w,
                          unsigned short* __restrict__ h) {
  int row = blockIdx.x;
  int t = threadIdx.x;
  const float4* xr = (const float4*)(x + (size_t)row * DIM);
  float4 v = xr[t];
  float ss = v.x * v.x + v.y * v.y + v.z * v.z + v.w * v.w;
#pragma unroll
  for (int o = 1; o < 64; o <<= 1) ss += __shfl_xor(ss, o);
  __shared__ float ps[4];
  if ((t & 63) == 0) ps[t >> 6] = ss;
  __syncthreads();
  float r = rsqrtf((ps[0] + ps[1] + ps[2] + ps[3]) * (1.0f / DIM) + 1e-6f);
  const float4* wr = (const float4*)w;
  float4 wv = wr[t];
  ushort4 o4;
  o4.x = f2bf(v.x * r * wv.x);
  o4.y = f2bf(v.y * r * wv.y);
  o4.z = f2bf(v.z * r * wv.z);
  o4.w = f2bf(v.w * r * wv.w);
  *(ushort4*)(h + (size_t)row * DIM + t * 4) = o4;
}

// ---------------- GEMM (m97 structure): C[M][Nc] = A[M][K] @ Bt[Nc][K]^T (+res) --------
// 128x128 tile, 4 waves (2x2), per-wave 64x64 = 4x4 frags of 16x16, BK=32.
// LDS is linear [128 rows][32 elems] per matrix; global_load_lds staging with
// rule-#21 XOR swizzle: chunk' = chunk ^ ((row>>1)&3) applied to BOTH the
// (inverse-swizzled) global source address and the ds_read address.
template <bool RES>
__global__ __launch_bounds__(256, 2) void gemm_f32(
    const unsigned short* __restrict__ A, const unsigned short* __restrict__ Bt,
    const float* __restrict__ res, float* __restrict__ C, int Nc, int K) {
  __shared__ __align__(16) unsigned short Asm[128 * 32];
  __shared__ __align__(16) unsigned short Bsm[128 * 32];
  int tid = threadIdx.x;
  int w = tid >> 6, l = tid & 63;
  int bm = blockIdx.y * 128, bn = blockIdx.x * 128;
  int wr = (w >> 1) * 64, wc = (w & 1) * 64;
  int c0 = l & 15, g = l >> 4;

  // staging: wave w stages rows [w*32, w*32+32) of A and B, 2 calls each (16 rows/call)
  int sr0 = w * 32 + (l >> 2);
  int sr1 = sr0 + 16;
  int sc0 = (((l & 3) ^ ((sr0 >> 1) & 3))) * 8;  // inverse-swizzled source chunk
  int sc1 = (((l & 3) ^ ((sr1 >> 1) & 3))) * 8;
  const unsigned short* gA0 = A + (size_t)(bm + sr0) * K + sc0;
  const unsigned short* gA1 = A + (size_t)(bm + sr1) * K + sc1;
  const unsigned short* gB0 = Bt + (size_t)(bn + sr0) * K + sc0;
  const unsigned short* gB1 = Bt + (size_t)(bn + sr1) * K + sc1;
  unsigned short* lA0 = &Asm[(w * 32) * 32];
  unsigned short* lA1 = &Asm[(w * 32 + 16) * 32];
  unsigned short* lB0 = &Bsm[(w * 32) * 32];
  unsigned short* lB1 = &Bsm[(w * 32 + 16) * 32];

  // swizzled fragment read offsets (elems)
  int aoff[4], boff[4];
#pragma unroll
  for (int m = 0; m < 4; m++) {
    int ra = wr + m * 16 + c0;
    aoff[m] = ra * 32 + (g ^ ((ra >> 1) & 3)) * 8;
    int rb = wc + m * 16 + c0;
    boff[m] = rb * 32 + (g ^ ((rb >> 1) & 3)) * 8;
  }

  f32x4 acc[4][4] = {};
  int nsteps = K / 32;
  for (int s = 0; s < nsteps; ++s) {
    __syncthreads();  // all ds_reads of previous tile drained
    glds16(gA0 + s * 32, lA0);
    glds16(gA1 + s * 32, lA1);
    glds16(gB0 + s * 32, lB0);
    glds16(gB1 + s * 32, lB1);
    __syncthreads();  // vmcnt(0) drain -> staging visible
    short8 af[4], bf[4];
#pragma unroll
    for (int m = 0; m < 4; m++) af[m] = *(const short8*)&Asm[aoff[m]];
#pragma unroll
    for (int n = 0; n < 4; n++) bf[n] = *(const short8*)&Bsm[boff[n]];
#pragma unroll
    for (int m = 0; m < 4; m++)
#pragma unroll
      for (int n = 0; n < 4; n++)
        acc[m][n] = __builtin_amdgcn_mfma_f32_16x16x32_bf16(af[m], bf[n], acc[m][n], 0, 0, 0);
  }
  int gq = l >> 4;
#pragma unroll
  for (int m = 0; m < 4; m++) {
#pragma unroll
    for (int i = 0; i < 4; i++) {
      int row = bm + wr + m * 16 + gq * 4 + i;
#pragma unroll
      for (int n = 0; n < 4; n++) {
        int col = bn + wc + n * 16 + c0;
        float v = acc[m][n][i];
        if (RES) v += res[(size_t)row * Nc + col];
        C[(size_t)row * Nc + col] = v;
      }
    }
  }
}

// ---------------- fused FFN13: g = silu(A@W1t^T) * (A@W3t^T), bf16 out ----------------
// 128x64 tile, 4 waves (2x2), per-wave 64x32 = 4x2 frags, two B matrices.
__global__ __launch_bounds__(256, 2) void gemm_ffn13(
    const unsigned short* __restrict__ A, const unsigned short* __restrict__ B1t,
    const unsigned short* __restrict__ B3t, unsigned short* __restrict__ G,
    int Nc, int K) {
  __shared__ __align__(16) unsigned short Asm[128 * 32];
  __shared__ __align__(16) unsigned short B1sm[64 * 32];
  __shared__ __align__(16) unsigned short B3sm[64 * 32];
  int tid = threadIdx.x;
  int w = tid >> 6, l = tid & 63;
  int bm = blockIdx.y * 128, bn = blockIdx.x * 64;
  int wr = (w >> 1) * 64, wc = (w & 1) * 32;
  int c0 = l & 15, g = l >> 4;

  // staging: A rows [w*32,+32) (2 calls), B1 rows [w*16,+16), B3 rows [w*16,+16)
  int sr0 = w * 32 + (l >> 2);
  int sr1 = sr0 + 16;
  int sb  = w * 16 + (l >> 2);
  int sc0 = (((l & 3) ^ ((sr0 >> 1) & 3))) * 8;
  int sc1 = (((l & 3) ^ ((sr1 >> 1) & 3))) * 8;
  int scb = (((l & 3) ^ ((sb  >> 1) & 3))) * 8;
  const unsigned short* gA0 = A + (size_t)(bm + sr0) * K + sc0;
  const unsigned short* gA1 = A + (size_t)(bm + sr1) * K + sc1;
  const unsigned short* gB1 = B1t + (size_t)(bn + sb) * K + scb;
  const unsigned short* gB3 = B3t + (size_t)(bn + sb) * K + scb;
  unsigned short* lA0 = &Asm[(w * 32) * 32];
  unsigned short* lA1 = &Asm[(w * 32 + 16) * 32];
  unsigned short* lB1 = &B1sm[(w * 16) * 32];
  unsigned short* lB3 = &B3sm[(w * 16) * 32];

  int aoff[4], boff[2];
#pragma unroll
  for (int m = 0; m < 4; m++) {
    int ra = wr + m * 16 + c0;
    aoff[m] = ra * 32 + (g ^ ((ra >> 1) & 3)) * 8;
  }
#pragma unroll
  for (int n = 0; n < 2; n++) {
    int rb = wc + n * 16 + c0;
    boff[n] = rb * 32 + (g ^ ((rb >> 1) & 3)) * 8;
  }

  f32x4 a1[4][2] = {};
  f32x4 a3[4][2] = {};
  int nsteps = K / 32;
  for (int s = 0; s < nsteps; ++s) {
    __syncthreads();
    glds16(gA0 + s * 32, lA0);
    glds16(gA1 + s * 32, lA1);
    glds16(gB1 + s * 32, lB1);
    glds16(gB3 + s * 32, lB3);
    __syncthreads();
    short8 af[4], b1f[2], b3f[2];
#pragma unroll
    for (int m = 0; m < 4; m++) af[m] = *(const short8*)&Asm[aoff[m]];
#pragma unroll
    for (int n = 0; n < 2; n++) {
      b1f[n] = *(const short8*)&B1sm[boff[n]];
      b3f[n] = *(const short8*)&B3sm[boff[n]];
    }
#pragma unroll
    for (int m = 0; m < 4; m++)
#pragma unroll
      for (int n = 0; n < 2; n++) {
        a1[m][n] = __builtin_amdgcn_mfma_f32_16x16x32_bf16(af[m], b1f[n], a1[m][n], 0, 0, 0);
        a3[m][n] = __builtin_amdgcn_mfma_f32_16x16x32_bf16(af[m], b3f[n], a3[m][n], 0, 0, 0);
      }
  }
  int gq = l >> 4;
#pragma unroll
  for (int m = 0; m < 4; m++) {
#pragma unroll
    for (int i = 0; i < 4; i++) {
      int row = bm + wr + m * 16 + gq * 4 + i;
#pragma unroll
      for (int n = 0; n < 2; n++) {
        int col = bn + wc + n * 16 + c0;
        float x1 = a1[m][n][i], x3 = a3[m][n][i];
        float sg = x1 / (1.0f + __expf(-x1));
        G[(size_t)row * Nc + col] = f2bf(sg * x3);
      }
    }
  }
}

// ---------------- qkv fp32 [B*N][1536] -> rope'd bf16 q/k + transposed v ----------------
__global__ void prep_qkv(const float* __restrict__ qkv, const float* __restrict__ cosb,
                         const float* __restrict__ sinb, unsigned short* __restrict__ qb,
                         unsigned short* __restrict__ kb, unsigned short* __restrict__ vtb) {
  int n = blockIdx.x, b = blockIdx.y;
  int t = threadIdx.x;
  const float* row = qkv + ((size_t)b * NN + n) * 1536;
#pragma unroll
  for (int p = t; p < 512; p += 256) {
    int head = p >> 5, j = p & 31;
    float xr = row[head * 64 + 2 * j], xi = row[head * 64 + 2 * j + 1];
    float c = cosb[n * 32 + j], s = sinb[n * 32 + j];
    size_t o = (((size_t)(b * NH + head)) * NN + n) * 64 + 2 * j;
    qb[o] = f2bf(xr * c - xi * s);
    qb[o + 1] = f2bf(xr * s + xi * c);
  }
  if (t < 128) {
    int kvh = t >> 5, j = t & 31;
    float xr = row[1024 + kvh * 64 + 2 * j], xi = row[1024 + kvh * 64 + 2 * j + 1];
    float c = cosb[n * 32 + j], s = sinb[n * 32 + j];
    size_t o = (((size_t)(b * NKV + kvh)) * NN + n) * 64 + 2 * j;
    kb[o] = f2bf(xr * c - xi * s);
    kb[o + 1] = f2bf(xr * s + xi * c);
  }
  {
    int kvh = t >> 6, d = t & 63;
    float v = row[1280 + kvh * 64 + d];
    vtb[(((size_t)(b * NKV + kvh)) * 64 + d) * NN + n] = f2bf(v);
  }
}

// ---------------- flash attention, causal, GQA (kv head = h % 4: jnp.tile) ----------
// v2: K/V are L2-resident (512 KB per (b,kvh), reused by 128 blocks) -> no LDS
// staging, no block-wide barriers in the KV loop. Only wave-local Psm handshake.
#define LK 72
__global__ __launch_bounds__(256, 4) void attn_k(
    const unsigned short* __restrict__ qb, const unsigned short* __restrict__ kb,
    const unsigned short* __restrict__ vtb, unsigned short* __restrict__ ob) {
  __shared__ __align__(16) unsigned short Psm[4 * 16 * LK];
  int qt = (int)gridDim.x - 1 - (int)blockIdx.x;  // long rows dispatch first
  int h = blockIdx.y, b = blockIdx.z;
  int kvh = h & 3;
  int tid = threadIdx.x, w = tid >> 6, l = tid & 63;
  int g = l >> 4, c0 = l & 15;

  const unsigned short* qrow_p = qb + (((size_t)(b * NH + h)) * NN + qt * 64 + w * 16 + c0) * 64;
  short8 q0 = *(const short8*)(qrow_p + g * 8);
  short8 q1 = *(const short8*)(qrow_p + 32 + g * 8);
  const unsigned short* Kg = kb + ((size_t)(b * NKV + kvh)) * NN * 64;
  const unsigned short* Vg = vtb + ((size_t)(b * NKV + kvh)) * 64 * NN;

  float m_r[4], l_r[4];
  f32x4 o_r[4] = {};
#pragma unroll
  for (int i = 0; i < 4; i++) { m_r[i] = -1e30f; l_r[i] = 0.0f; }

  int nkt = qt + 1;
  for (int kt = 0; kt < nkt; ++kt) {
    int n0 = kt * 64;
    // S = Q K^T, K fragments straight from global (L2-hit)
    f32x4 s[4];
#pragma unroll
    for (int sub = 0; sub < 4; sub++) {
      const unsigned short* kr = Kg + (size_t)(n0 + sub * 16 + c0) * 64;
      short8 kf0 = *(const short8*)(kr + g * 8);
      short8 kf1 = *(const short8*)(kr + 32 + g * 8);
      f32x4 a = {0.0f, 0.0f, 0.0f, 0.0f};
      a = __builtin_amdgcn_mfma_f32_16x16x32_bf16(q0, kf0, a, 0, 0, 0);
      a = __builtin_amdgcn_mfma_f32_16x16x32_bf16(q1, kf1, a, 0, 0, 0);
      s[sub] = a;
    }
    bool diag = (kt == qt);
#pragma unroll
    for (int i = 0; i < 4; i++) {
      int qg = qt * 64 + w * 16 + g * 4 + i;
      float sv[4];
#pragma unroll
      for (int sub = 0; sub < 4; sub++) {
        float v = s[sub][i] * 0.125f;
        if (diag && (n0 + sub * 16 + c0 > qg)) v = -1e30f;
        sv[sub] = v;
      }
      float pm = fmaxf(fmaxf(sv[0], sv[1]), fmaxf(sv[2], sv[3]));
#pragma unroll
      for (int o = 1; o < 16; o <<= 1) pm = fmaxf(pm, __shfl_xor(pm, o));
      float mn = fmaxf(m_r[i], pm);
      float alpha = __expf(m_r[i] - mn);
      m_r[i] = mn;
      float rs = 0.0f;
#pragma unroll
      for (int sub = 0; sub < 4; sub++) {
        float p = __expf(sv[sub] - mn);
        rs += p;
        Psm[(w * 16 + g * 4 + i) * LK + sub * 16 + c0] = f2bf(p);
      }
#pragma unroll
      for (int o = 1; o < 16; o <<= 1) rs += __shfl_xor(rs, o);
      l_r[i] = l_r[i] * alpha + rs;
#pragma unroll
      for (int vs = 0; vs < 4; vs++) o_r[vs][i] *= alpha;
    }
    // wave-local P visibility: drain DS, pin order (rule #18)
    asm volatile("s_waitcnt lgkmcnt(0)" ::: "memory");
    __builtin_amdgcn_sched_barrier(0);
    // O += P @ V, V^T fragments straight from global
#pragma unroll
    for (int half = 0; half < 2; half++) {
      short8 pa = *(const short8*)&Psm[(w * 16 + c0) * LK + half * 32 + g * 8];
#pragma unroll
      for (int vs = 0; vs < 4; vs++) {
        const unsigned short* vr = Vg + (size_t)(vs * 16 + c0) * NN + n0;
        short8 vf = *(const short8*)(vr + half * 32 + g * 8);
        o_r[vs] = __builtin_amdgcn_mfma_f32_16x16x32_bf16(pa, vf, o_r[vs], 0, 0, 0);
      }
    }
  }
#pragma unroll
  for (int i = 0; i < 4; i++) {
    float inv = 1.0f / l_r[i];
    int orow = qt * 64 + w * 16 + g * 4 + i;
    size_t base = ((size_t)b * NN + orow) * 1024 + h * 64;
#pragma unroll
    for (int vs = 0; vs < 4; vs++)
      ob[base + vs * 16 + c0] = f2bf(o_r[vs][i] * inv);
  }
}

// ---------------- launcher ----------------
extern "C" void kernel_launch(void* const* d_in, const int* in_sizes, int n_in,
                              void* d_out, int out_size, void* d_ws, size_t ws_size,
                              hipStream_t stream) {
  (void)in_sizes; (void)n_in; (void)out_size; (void)ws_size;
  const float* x    = (const float*)d_in[0];
  const float* w_an = (const float*)d_in[1];
  const float* w_fn = (const float*)d_in[2];
  const float* Wq   = (const float*)d_in[3];
  const float* Wkv  = (const float*)d_in[4];
  const float* Wo   = (const float*)d_in[5];
  const float* W1   = (const float*)d_in[6];
  const float* W2   = (const float*)d_in[7];
  const float* W3   = (const float*)d_in[8];
  const float* cosb = (const float*)d_in[9];
  const float* sinb = (const float*)d_in[10];
  float* out = (float*)d_out;

  char* ws = (char*)d_ws;
  size_t off = 0;
  auto take = [&](size_t bytes) {
    size_t r = off;
    off += (bytes + 255) & ~(size_t)255;
    return r;
  };
  unsigned short* WqkvT = (unsigned short*)(ws + take((size_t)1536 * 1024 * 2));
  unsigned short* WoT   = (unsigned short*)(ws + take((size_t)1024 * 1024 * 2));
  unsigned short* W1T   = (unsigned short*)(ws + take((size_t)2688 * 1024 * 2));
  unsigned short* W3T   = (unsigned short*)(ws + take((size_t)2688 * 1024 * 2));
  unsigned short* W2T   = (unsigned short*)(ws + take((size_t)2688 * 1024 * 2));
  unsigned short* hA    = (unsigned short*)(ws + take((size_t)MM * DIM * 2));  // reused as h2
  char* qkv_region = ws + take((size_t)MM * 1536 * 4);  // reused as g
  float* qkv = (float*)qkv_region;
  unsigned short* gbuf = (unsigned short*)qkv_region;
  unsigned short* qbuf = (unsigned short*)(ws + take((size_t)MM * DIM * 2));
  unsigned short* kbuf = (unsigned short*)(ws + take((size_t)BB * NKV * NN * HD * 2));
  unsigned short* vtb  = (unsigned short*)(ws + take((size_t)BB * NKV * NN * HD * 2));
  unsigned short* obuf = (unsigned short*)(ws + take((size_t)MM * DIM * 2));
  float* x2 = (float*)(ws + take((size_t)MM * DIM * 4));

  transpose_k<<<dim3(1024 / 32, 1024 / 32), 256, 0, stream>>>(Wq, WqkvT, 1024, 1024);
  transpose_k<<<dim3(512 / 32, 1024 / 32), 256, 0, stream>>>(Wkv, WqkvT + (size_t)1024 * 1024, 1024, 512);
  transpose_k<<<dim3(1024 / 32, 1024 / 32), 256, 0, stream>>>(Wo, WoT, 1024, 1024);
  transpose_k<<<dim3(2688 / 32, 1024 / 32), 256, 0, stream>>>(W1, W1T, 1024, 2688);
  transpose_k<<<dim3(2688 / 32, 1024 / 32), 256, 0, stream>>>(W3, W3T, 1024, 2688);
  transpose_k<<<dim3(1024 / 32, 2688 / 32), 256, 0, stream>>>(W2, W2T, 2688, 1024);

  rmsnorm_k<<<MM, 256, 0, stream>>>(x, w_an, hA);
  gemm_f32<false><<<dim3(1536 / 128, MM / 128), 256, 0, stream>>>(hA, WqkvT, nullptr, qkv, 1536, 1024);
  prep_qkv<<<dim3(NN, BB), 256, 0, stream>>>(qkv, cosb, sinb, qbuf, kbuf, vtb);
  attn_k<<<dim3(NN / 64, NH, BB), 256, 0, stream>>>(qbuf, kbuf, vtb, obuf);
  gemm_f32<true><<<dim3(1024 / 128, MM / 128), 256, 0, stream>>>(obuf, WoT, x, x2, 1024, 1024);
  rmsnorm_k<<<MM, 256, 0, stream>>>(x2, w_fn, hA);
  gemm_ffn13<<<dim3(INTER / 64, MM / 128), 256, 0, stream>>>(hA, W1T, W3T, gbuf, INTER, 1024);
  gemm_f32<true><<<dim3(1024 / 128, MM / 128), 256, 0, stream>>>(gbuf, W2T, x2, out, 1024, 2688);
}

// Round 3
// 341.402 us; speedup vs baseline: 1.3179x; 1.3179x over previous
//
#include <hip/hip_runtime.h>

#define DIM 1024
#define NH 16
#define NKV 4
#define HD 64
#define INTER 2688
#define BB 2
#define NN 2048
#define MM (BB*NN)

typedef __attribute__((ext_vector_type(4))) float f32x4;
typedef __attribute__((ext_vector_type(8))) short short8;

__device__ __forceinline__ unsigned short f2bf(float f) {
  union { float f; unsigned u; } v; v.f = f;
  unsigned r = v.u + 0x7fffu + ((v.u >> 16) & 1u);
  return (unsigned short)(r >> 16);
}

// async global->LDS, 16B per lane; LDS dest = wave-uniform base + lane*16
__device__ __forceinline__ void glds16(const unsigned short* g, unsigned short* l) {
  __builtin_amdgcn_global_load_lds(
      (const __attribute__((address_space(1))) void*)g,
      (__attribute__((address_space(3))) void*)l, 16, 0, 0);
}

// ---------------- transpose fp32 [K][Nc] -> bf16 [Nc][K] ----------------
__global__ void transpose_k(const float* __restrict__ W, unsigned short* __restrict__ Wt,
                            int K, int Nc) {
  __shared__ float tile[32][33];
  int n0 = blockIdx.x * 32, k0 = blockIdx.y * 32;
  int tx = threadIdx.x & 31, ty = threadIdx.x >> 5;
#pragma unroll
  for (int i = 0; i < 32; i += 8)
    tile[ty + i][tx] = W[(size_t)(k0 + ty + i) * Nc + n0 + tx];
  __syncthreads();
#pragma unroll
  for (int i = 0; i < 32; i += 8)
    Wt[(size_t)(n0 + ty + i) * K + k0 + tx] = f2bf(tile[tx][ty + i]);
}

// ---------------- RMSNorm: fp32 [rows][1024] -> bf16 ----------------
__global__ void rmsnorm_k(const float* __restrict__ x, const float* __restrict__ w,
                          unsigned short* __restrict__ h) {
  int row = blockIdx.x;
  int t = threadIdx.x;
  const float4* xr = (const float4*)(x + (size_t)row * DIM);
  float4 v = xr[t];
  float ss = v.x * v.x + v.y * v.y + v.z * v.z + v.w * v.w;
#pragma unroll
  for (int o = 1; o < 64; o <<= 1) ss += __shfl_xor(ss, o);
  __shared__ float ps[4];
  if ((t & 63) == 0) ps[t >> 6] = ss;
  __syncthreads();
  float r = rsqrtf((ps[0] + ps[1] + ps[2] + ps[3]) * (1.0f / DIM) + 1e-6f);
  const float4* wr = (const float4*)w;
  float4 wv = wr[t];
  ushort4 o4;
  o4.x = f2bf(v.x * r * wv.x);
  o4.y = f2bf(v.y * r * wv.y);
  o4.z = f2bf(v.z * r * wv.z);
  o4.w = f2bf(v.w * r * wv.w);
  *(ushort4*)(h + (size_t)row * DIM + t * 4) = o4;
}

// ---------------- GEMM: C[M][Nc] = A[M][K] @ Bt[Nc][K]^T (+res), fp32 out ----------------
// 128x128 tile, 4 waves (2x2), 4x4 frags/wave, BK=32, glds staging,
// XOR swizzle chunk^((row>>1)&3), 2-phase double-buffer, 1 barrier/step.
template <bool RES>
__global__ __launch_bounds__(256, 3) void gemm_f32(
    const unsigned short* __restrict__ A, const unsigned short* __restrict__ Bt,
    const float* __restrict__ res, float* __restrict__ C, int Nc, int K) {
  __shared__ __align__(16) unsigned short Asm[2 * 128 * 32];
  __shared__ __align__(16) unsigned short Bsm[2 * 128 * 32];
  int tid = threadIdx.x;
  int w = tid >> 6, l = tid & 63;
  int bm = blockIdx.y * 128, bn = blockIdx.x * 128;
  int wr = (w >> 1) * 64, wc = (w & 1) * 64;
  int c0 = l & 15, g = l >> 4;

  // staging: wave w stages rows [w*32, w*32+32), 2 calls (16 rows each)
  int sr = w * 32 + (l >> 2);
  int sc = ((l & 3) ^ ((sr >> 1) & 3)) * 8;  // (sr+16)>>1 has same &3 -> same chunk
  const unsigned short* gA0 = A + (size_t)(bm + sr) * K + sc;
  const unsigned short* gA1 = A + (size_t)(bm + sr + 16) * K + sc;
  const unsigned short* gB0 = Bt + (size_t)(bn + sr) * K + sc;
  const unsigned short* gB1 = Bt + (size_t)(bn + sr + 16) * K + sc;
  int ls0 = (w * 32) * 32, ls1 = (w * 32 + 16) * 32;

  int aoff[4], boff[4];
#pragma unroll
  for (int m = 0; m < 4; m++) {
    int ra = wr + m * 16 + c0;
    aoff[m] = ra * 32 + (g ^ ((ra >> 1) & 3)) * 8;
    int rb = wc + m * 16 + c0;
    boff[m] = rb * 32 + (g ^ ((rb >> 1) & 3)) * 8;
  }

  f32x4 acc[4][4] = {};
  int nsteps = K / 32;
  // prologue: stage tile 0 into buf 0
  glds16(gA0, &Asm[ls0]);
  glds16(gA1, &Asm[ls1]);
  glds16(gB0, &Bsm[ls0]);
  glds16(gB1, &Bsm[ls1]);
  __syncthreads();
  int buf = 0;
  for (int s = 0; s < nsteps; ++s) {
    int nb = buf ^ 1;
    if (s + 1 < nsteps) {
      int ko = (s + 1) * 32;
      glds16(gA0 + ko, &Asm[nb * 4096 + ls0]);
      glds16(gA1 + ko, &Asm[nb * 4096 + ls1]);
      glds16(gB0 + ko, &Bsm[nb * 4096 + ls0]);
      glds16(gB1 + ko, &Bsm[nb * 4096 + ls1]);
    }
    const unsigned short* As = &Asm[buf * 4096];
    const unsigned short* Bs = &Bsm[buf * 4096];
    short8 af[4], bf[4];
#pragma unroll
    for (int m = 0; m < 4; m++) af[m] = *(const short8*)&As[aoff[m]];
#pragma unroll
    for (int n = 0; n < 4; n++) bf[n] = *(const short8*)&Bs[boff[n]];
#pragma unroll
    for (int m = 0; m < 4; m++)
#pragma unroll
      for (int n = 0; n < 4; n++)
        acc[m][n] = __builtin_amdgcn_mfma_f32_16x16x32_bf16(af[m], bf[n], acc[m][n], 0, 0, 0);
    __syncthreads();  // drains vmcnt(0)+lgkmcnt(0): staged tile visible, reads done
    buf = nb;
  }
  int gq = l >> 4;
#pragma unroll
  for (int m = 0; m < 4; m++) {
#pragma unroll
    for (int i = 0; i < 4; i++) {
      int row = bm + wr + m * 16 + gq * 4 + i;
#pragma unroll
      for (int n = 0; n < 4; n++) {
        int col = bn + wc + n * 16 + c0;
        float v = acc[m][n][i];
        if (RES) v += res[(size_t)row * Nc + col];
        C[(size_t)row * Nc + col] = v;
      }
    }
  }
}

// ---------------- fused FFN13: g = silu(A@W1t^T) * (A@W3t^T), bf16 out ----------------
__global__ __launch_bounds__(256, 3) void gemm_ffn13(
    const unsigned short* __restrict__ A, const unsigned short* __restrict__ B1t,
    const unsigned short* __restrict__ B3t, unsigned short* __restrict__ G,
    int Nc, int K) {
  __shared__ __align__(16) unsigned short Asm[2 * 128 * 32];
  __shared__ __align__(16) unsigned short B1sm[2 * 64 * 32];
  __shared__ __align__(16) unsigned short B3sm[2 * 64 * 32];
  int tid = threadIdx.x;
  int w = tid >> 6, l = tid & 63;
  int bm = blockIdx.y * 128, bn = blockIdx.x * 64;
  int wr = (w >> 1) * 64, wc = (w & 1) * 32;
  int c0 = l & 15, g = l >> 4;

  int sr = w * 32 + (l >> 2);
  int sb = w * 16 + (l >> 2);
  int sc  = ((l & 3) ^ ((sr >> 1) & 3)) * 8;
  int scb = ((l & 3) ^ ((sb >> 1) & 3)) * 8;
  const unsigned short* gA0 = A + (size_t)(bm + sr) * K + sc;
  const unsigned short* gA1 = A + (size_t)(bm + sr + 16) * K + sc;
  const unsigned short* gB1 = B1t + (size_t)(bn + sb) * K + scb;
  const unsigned short* gB3 = B3t + (size_t)(bn + sb) * K + scb;
  int ls0 = (w * 32) * 32, ls1 = (w * 32 + 16) * 32, lsb = (w * 16) * 32;

  int aoff[4], boff[2];
#pragma unroll
  for (int m = 0; m < 4; m++) {
    int ra = wr + m * 16 + c0;
    aoff[m] = ra * 32 + (g ^ ((ra >> 1) & 3)) * 8;
  }
#pragma unroll
  for (int n = 0; n < 2; n++) {
    int rb = wc + n * 16 + c0;
    boff[n] = rb * 32 + (g ^ ((rb >> 1) & 3)) * 8;
  }

  f32x4 a1[4][2] = {};
  f32x4 a3[4][2] = {};
  int nsteps = K / 32;
  glds16(gA0, &Asm[ls0]);
  glds16(gA1, &Asm[ls1]);
  glds16(gB1, &B1sm[lsb]);
  glds16(gB3, &B3sm[lsb]);
  __syncthreads();
  int buf = 0;
  for (int s = 0; s < nsteps; ++s) {
    int nb = buf ^ 1;
    if (s + 1 < nsteps) {
      int ko = (s + 1) * 32;
      glds16(gA0 + ko, &Asm[nb * 4096 + ls0]);
      glds16(gA1 + ko, &Asm[nb * 4096 + ls1]);
      glds16(gB1 + ko, &B1sm[nb * 2048 + lsb]);
      glds16(gB3 + ko, &B3sm[nb * 2048 + lsb]);
    }
    const unsigned short* As = &Asm[buf * 4096];
    const unsigned short* B1s = &B1sm[buf * 2048];
    const unsigned short* B3s = &B3sm[buf * 2048];
    short8 af[4], b1f[2], b3f[2];
#pragma unroll
    for (int m = 0; m < 4; m++) af[m] = *(const short8*)&As[aoff[m]];
#pragma unroll
    for (int n = 0; n < 2; n++) {
      b1f[n] = *(const short8*)&B1s[boff[n]];
      b3f[n] = *(const short8*)&B3s[boff[n]];
    }
#pragma unroll
    for (int m = 0; m < 4; m++)
#pragma unroll
      for (int n = 0; n < 2; n++) {
        a1[m][n] = __builtin_amdgcn_mfma_f32_16x16x32_bf16(af[m], b1f[n], a1[m][n], 0, 0, 0);
        a3[m][n] = __builtin_amdgcn_mfma_f32_16x16x32_bf16(af[m], b3f[n], a3[m][n], 0, 0, 0);
      }
    __syncthreads();
    buf = nb;
  }
  int gq = l >> 4;
#pragma unroll
  for (int m = 0; m < 4; m++) {
#pragma unroll
    for (int i = 0; i < 4; i++) {
      int row = bm + wr + m * 16 + gq * 4 + i;
#pragma unroll
      for (int n = 0; n < 2; n++) {
        int col = bn + wc + n * 16 + c0;
        float x1 = a1[m][n][i], x3 = a3[m][n][i];
        float sg = x1 / (1.0f + __expf(-x1));
        G[(size_t)row * Nc + col] = f2bf(sg * x3);
      }
    }
  }
}

// ---------------- qkv fp32 [B*N][1536] -> rope'd bf16 q/k + transposed v ----------------
__global__ void prep_qkv(const float* __restrict__ qkv, const float* __restrict__ cosb,
                         const float* __restrict__ sinb, unsigned short* __restrict__ qb,
                         unsigned short* __restrict__ kb, unsigned short* __restrict__ vtb) {
  int n = blockIdx.x, b = blockIdx.y;
  int t = threadIdx.x;
  const float* row = qkv + ((size_t)b * NN + n) * 1536;
#pragma unroll
  for (int p = t; p < 512; p += 256) {
    int head = p >> 5, j = p & 31;
    float xr = row[head * 64 + 2 * j], xi = row[head * 64 + 2 * j + 1];
    float c = cosb[n * 32 + j], s = sinb[n * 32 + j];
    size_t o = (((size_t)(b * NH + head)) * NN + n) * 64 + 2 * j;
    qb[o] = f2bf(xr * c - xi * s);
    qb[o + 1] = f2bf(xr * s + xi * c);
  }
  if (t < 128) {
    int kvh = t >> 5, j = t & 31;
    float xr = row[1024 + kvh * 64 + 2 * j], xi = row[1024 + kvh * 64 + 2 * j + 1];
    float c = cosb[n * 32 + j], s = sinb[n * 32 + j];
    size_t o = (((size_t)(b * NKV + kvh)) * NN + n) * 64 + 2 * j;
    kb[o] = f2bf(xr * c - xi * s);
    kb[o + 1] = f2bf(xr * s + xi * c);
  }
  {
    int kvh = t >> 6, d = t & 63;
    float v = row[1280 + kvh * 64 + d];
    vtb[(((size_t)(b * NKV + kvh)) * 64 + d) * NN + n] = f2bf(v);
  }
}

// ---------------- flash attention, causal, GQA (kv head = h % 4: jnp.tile) ----------
// v3: glds-staged K/V with XOR swizzle chunk^(row&7), 2-phase double-buffer,
// one barrier per KV-tile, setprio around MFMA clusters.
#define LK 72
__global__ __launch_bounds__(256, 3) void attn_k(
    const unsigned short* __restrict__ qb, const unsigned short* __restrict__ kb,
    const unsigned short* __restrict__ vtb, unsigned short* __restrict__ ob) {
  __shared__ __align__(16) unsigned short Ksm[2 * 64 * 64];
  __shared__ __align__(16) unsigned short Vsm[2 * 64 * 64];
  __shared__ __align__(16) unsigned short Psm[4 * 16 * LK];
  int qt = (int)gridDim.x - 1 - (int)blockIdx.x;  // long rows dispatch first
  int h = blockIdx.y, b = blockIdx.z;
  int kvh = h & 3;
  int tid = threadIdx.x, w = tid >> 6, l = tid & 63;
  int g = l >> 4, c0 = l & 15;

  const unsigned short* qrow_p = qb + (((size_t)(b * NH + h)) * NN + qt * 64 + w * 16 + c0) * 64;
  short8 q0 = *(const short8*)(qrow_p + g * 8);
  short8 q1 = *(const short8*)(qrow_p + 32 + g * 8);
  const unsigned short* Kg = kb + ((size_t)(b * NKV + kvh)) * NN * 64;
  const unsigned short* Vg = vtb + ((size_t)(b * NKV + kvh)) * 64 * NN;

  // staging: wave w stages K/V rows [w*16, w*16+16), 2 glds calls each.
  // pre-swizzled source chunk: logical chunk (l&7) stored at position (l&7),
  // so source chunk = (l&7) ^ (ldsrow&7), ldsrow&7 == l>>3 for both calls.
  int schunk = (l & 7) ^ (l >> 3);
  const unsigned short* gK0 = Kg + (size_t)(w * 16 + (l >> 3)) * 64 + schunk * 8;
  const unsigned short* gK1 = gK0 + 8 * 64;
  const unsigned short* gV0 = Vg + (size_t)(w * 16 + (l >> 3)) * NN + schunk * 8;
  const unsigned short* gV1 = gV0 + 8 * NN;

  float m_r[4], l_r[4];
  f32x4 o_r[4] = {};
#pragma unroll
  for (int i = 0; i < 4; i++) { m_r[i] = -1e30f; l_r[i] = 0.0f; }

  int nkt = qt + 1;
  // prologue: stage tile 0 into buf 0
  {
    unsigned short* kd = &Ksm[(w * 16) * 64];
    unsigned short* vd = &Vsm[(w * 16) * 64];
    glds16(gK0, kd); glds16(gK1, kd + 8 * 64);
    glds16(gV0, vd); glds16(gV1, vd + 8 * 64);
  }
  __syncthreads();
  int buf = 0;
  for (int kt = 0; kt < nkt; ++kt) {
    int n0 = kt * 64;
    if (kt + 1 < nkt) {
      int nb = buf ^ 1;
      unsigned short* kd = &Ksm[nb * 4096 + (w * 16) * 64];
      unsigned short* vd = &Vsm[nb * 4096 + (w * 16) * 64];
      glds16(gK0 + (size_t)(n0 + 64) * 64, kd);
      glds16(gK1 + (size_t)(n0 + 64) * 64, kd + 8 * 64);
      glds16(gV0 + n0 + 64, vd);
      glds16(gV1 + n0 + 64, vd + 8 * 64);
    }
    const unsigned short* Ks = &Ksm[buf * 4096];
    const unsigned short* Vs = &Vsm[buf * 4096];
    // S = Q K^T  (16 q-rows x 64 k-cols per wave); swizzled ds_reads
    f32x4 s[4];
    int rsw = c0 & 7;
    __builtin_amdgcn_s_setprio(1);
#pragma unroll
    for (int sub = 0; sub < 4; sub++) {
      int r = sub * 16 + c0;
      short8 kf0 = *(const short8*)&Ks[r * 64 + (g ^ rsw) * 8];
      short8 kf1 = *(const short8*)&Ks[r * 64 + ((g + 4) ^ rsw) * 8];
      f32x4 a = {0.0f, 0.0f, 0.0f, 0.0f};
      a = __builtin_amdgcn_mfma_f32_16x16x32_bf16(q0, kf0, a, 0, 0, 0);
      a = __builtin_amdgcn_mfma_f32_16x16x32_bf16(q1, kf1, a, 0, 0, 0);
      s[sub] = a;
    }
    __builtin_amdgcn_s_setprio(0);
    bool diag = (kt == qt);
#pragma unroll
    for (int i = 0; i < 4; i++) {
      int qg = qt * 64 + w * 16 + g * 4 + i;
      float sv[4];
#pragma unroll
      for (int sub = 0; sub < 4; sub++) {
        float v = s[sub][i] * 0.125f;
        if (diag && (n0 + sub * 16 + c0 > qg)) v = -1e30f;
        sv[sub] = v;
      }
      float pm = fmaxf(fmaxf(sv[0], sv[1]), fmaxf(sv[2], sv[3]));
#pragma unroll
      for (int o = 1; o < 16; o <<= 1) pm = fmaxf(pm, __shfl_xor(pm, o));
      float mn = fmaxf(m_r[i], pm);
      float alpha = __expf(m_r[i] - mn);
      m_r[i] = mn;
      float rs = 0.0f;
#pragma unroll
      for (int sub = 0; sub < 4; sub++) {
        float p = __expf(sv[sub] - mn);
        rs += p;
        Psm[(w * 16 + g * 4 + i) * LK + sub * 16 + c0] = f2bf(p);
      }
#pragma unroll
      for (int o = 1; o < 16; o <<= 1) rs += __shfl_xor(rs, o);
      l_r[i] = l_r[i] * alpha + rs;
#pragma unroll
      for (int vs = 0; vs < 4; vs++) o_r[vs][i] *= alpha;
    }
    // wave-local P visibility: drain DS, pin order (rule #18)
    asm volatile("s_waitcnt lgkmcnt(0)" ::: "memory");
    __builtin_amdgcn_sched_barrier(0);
    // O += P @ V  (V^T tile, swizzled ds_reads)
    __builtin_amdgcn_s_setprio(1);
#pragma unroll
    for (int half = 0; half < 2; half++) {
      short8 pa = *(const short8*)&Psm[(w * 16 + c0) * LK + half * 32 + g * 8];
#pragma unroll
      for (int vs = 0; vs < 4; vs++) {
        int r = vs * 16 + c0;
        short8 vf = *(const short8*)&Vs[r * 64 + ((half * 4 + g) ^ rsw) * 8];
        o_r[vs] = __builtin_amdgcn_mfma_f32_16x16x32_bf16(pa, vf, o_r[vs], 0, 0, 0);
      }
    }
    __builtin_amdgcn_s_setprio(0);
    __syncthreads();  // vmcnt(0): next tile staged; lgkmcnt(0): buf reads done
    buf ^= 1;
  }
#pragma unroll
  for (int i = 0; i < 4; i++) {
    float inv = 1.0f / l_r[i];
    int orow = qt * 64 + w * 16 + g * 4 + i;
    size_t base = ((size_t)b * NN + orow) * 1024 + h * 64;
#pragma unroll
    for (int vs = 0; vs < 4; vs++)
      ob[base + vs * 16 + c0] = f2bf(o_r[vs][i] * inv);
  }
}

// ---------------- launcher ----------------
extern "C" void kernel_launch(void* const* d_in, const int* in_sizes, int n_in,
                              void* d_out, int out_size, void* d_ws, size_t ws_size,
                              hipStream_t stream) {
  (void)in_sizes; (void)n_in; (void)out_size; (void)ws_size;
  const float* x    = (const float*)d_in[0];
  const float* w_an = (const float*)d_in[1];
  const float* w_fn = (const float*)d_in[2];
  const float* Wq   = (const float*)d_in[3];
  const float* Wkv  = (const float*)d_in[4];
  const float* Wo   = (const float*)d_in[5];
  const float* W1   = (const float*)d_in[6];
  const float* W2   = (const float*)d_in[7];
  const float* W3   = (const float*)d_in[8];
  const float* cosb = (const float*)d_in[9];
  const float* sinb = (const float*)d_in[10];
  float* out = (float*)d_out;

  char* ws = (char*)d_ws;
  size_t off = 0;
  auto take = [&](size_t bytes) {
    size_t r = off;
    off += (bytes + 255) & ~(size_t)255;
    return r;
  };
  unsigned short* WqkvT = (unsigned short*)(ws + take((size_t)1536 * 1024 * 2));
  unsigned short* WoT   = (unsigned short*)(ws + take((size_t)1024 * 1024 * 2));
  unsigned short* W1T   = (unsigned short*)(ws + take((size_t)2688 * 1024 * 2));
  unsigned short* W3T   = (unsigned short*)(ws + take((size_t)2688 * 1024 * 2));
  unsigned short* W2T   = (unsigned short*)(ws + take((size_t)2688 * 1024 * 2));
  unsigned short* hA    = (unsigned short*)(ws + take((size_t)MM * DIM * 2));  // reused as h2
  char* qkv_region = ws + take((size_t)MM * 1536 * 4);  // reused as g
  float* qkv = (float*)qkv_region;
  unsigned short* gbuf = (unsigned short*)qkv_region;
  unsigned short* qbuf = (unsigned short*)(ws + take((size_t)MM * DIM * 2));
  unsigned short* kbuf = (unsigned short*)(ws + take((size_t)BB * NKV * NN * HD * 2));
  unsigned short* vtb  = (unsigned short*)(ws + take((size_t)BB * NKV * NN * HD * 2));
  unsigned short* obuf = (unsigned short*)(ws + take((size_t)MM * DIM * 2));
  float* x2 = (float*)(ws + take((size_t)MM * DIM * 4));

  transpose_k<<<dim3(1024 / 32, 1024 / 32), 256, 0, stream>>>(Wq, WqkvT, 1024, 1024);
  transpose_k<<<dim3(512 / 32, 1024 / 32), 256, 0, stream>>>(Wkv, WqkvT + (size_t)1024 * 1024, 1024, 512);
  transpose_k<<<dim3(1024 / 32, 1024 / 32), 256, 0, stream>>>(Wo, WoT, 1024, 1024);
  transpose_k<<<dim3(2688 / 32, 1024 / 32), 256, 0, stream>>>(W1, W1T, 1024, 2688);
  transpose_k<<<dim3(2688 / 32, 1024 / 32), 256, 0, stream>>>(W3, W3T, 1024, 2688);
  transpose_k<<<dim3(1024 / 32, 2688 / 32), 256, 0, stream>>>(W2, W2T, 2688, 1024);

  rmsnorm_k<<<MM, 256, 0, stream>>>(x, w_an, hA);
  gemm_f32<false><<<dim3(1536 / 128, MM / 128), 256, 0, stream>>>(hA, WqkvT, nullptr, qkv, 1536, 1024);
  prep_qkv<<<dim3(NN, BB), 256, 0, stream>>>(qkv, cosb, sinb, qbuf, kbuf, vtb);
  attn_k<<<dim3(NN / 64, NH, BB), 256, 0, stream>>>(qbuf, kbuf, vtb, obuf);
  gemm_f32<true><<<dim3(1024 / 128, MM / 128), 256, 0, stream>>>(obuf, WoT, x, x2, 1024, 1024);
  rmsnorm_k<<<MM, 256, 0, stream>>>(x2, w_fn, hA);
  gemm_ffn13<<<dim3(INTER / 64, MM / 128), 256, 0, stream>>>(hA, W1T, W3T, gbuf, INTER, 1024);
  gemm_f32<true><<<dim3(1024 / 128, MM / 128), 256, 0, stream>>>(gbuf, W2T, x2, out, 1024, 2688);
}

// Round 4
// 269.693 us; speedup vs baseline: 1.6683x; 1.2659x over previous
//
#include <hip/hip_runtime.h>

#define DIM 1024
#define NH 16
#define NKV 4
#define HD 64
#define INTER 2688
#define BB 2
#define NN 2048
#define MM (BB*NN)

typedef __attribute__((ext_vector_type(4))) float f32x4;
typedef __attribute__((ext_vector_type(16))) float f32x16;
typedef __attribute__((ext_vector_type(8))) short short8;

#define CROW(r,h) ((((r)&3)) + 8*((r)>>2) + 4*(h))

__device__ __forceinline__ unsigned short f2bf(float f) {
  union { float f; unsigned u; } v; v.f = f;
  unsigned r = v.u + 0x7fffu + ((v.u >> 16) & 1u);
  return (unsigned short)(r >> 16);
}

// async global->LDS, 16B per lane; LDS dest = wave-uniform base + lane*16
__device__ __forceinline__ void glds16(const unsigned short* g, unsigned short* l) {
  __builtin_amdgcn_global_load_lds(
      (const __attribute__((address_space(1))) void*)g,
      (__attribute__((address_space(3))) void*)l, 16, 0, 0);
}

// ---------------- transpose fp32 [K][Nc] -> bf16 [Nc][K] ----------------
__global__ void transpose_k(const float* __restrict__ W, unsigned short* __restrict__ Wt,
                            int K, int Nc) {
  __shared__ float tile[32][33];
  int n0 = blockIdx.x * 32, k0 = blockIdx.y * 32;
  int tx = threadIdx.x & 31, ty = threadIdx.x >> 5;
#pragma unroll
  for (int i = 0; i < 32; i += 8)
    tile[ty + i][tx] = W[(size_t)(k0 + ty + i) * Nc + n0 + tx];
  __syncthreads();
#pragma unroll
  for (int i = 0; i < 32; i += 8)
    Wt[(size_t)(n0 + ty + i) * K + k0 + tx] = f2bf(tile[tx][ty + i]);
}

// ---------------- RMSNorm: fp32 [rows][1024] -> bf16 ----------------
__global__ void rmsnorm_k(const float* __restrict__ x, const float* __restrict__ w,
                          unsigned short* __restrict__ h) {
  int row = blockIdx.x;
  int t = threadIdx.x;
  const float4* xr = (const float4*)(x + (size_t)row * DIM);
  float4 v = xr[t];
  float ss = v.x * v.x + v.y * v.y + v.z * v.z + v.w * v.w;
#pragma unroll
  for (int o = 1; o < 64; o <<= 1) ss += __shfl_xor(ss, o);
  __shared__ float ps[4];
  if ((t & 63) == 0) ps[t >> 6] = ss;
  __syncthreads();
  float r = rsqrtf((ps[0] + ps[1] + ps[2] + ps[3]) * (1.0f / DIM) + 1e-6f);
  const float4* wr = (const float4*)w;
  float4 wv = wr[t];
  ushort4 o4;
  o4.x = f2bf(v.x * r * wv.x);
  o4.y = f2bf(v.y * r * wv.y);
  o4.z = f2bf(v.z * r * wv.z);
  o4.w = f2bf(v.w * r * wv.w);
  *(ushort4*)(h + (size_t)row * DIM + t * 4) = o4;
}

// ---------------- GEMM: C[M][Nc] = A[M][K] @ Bt[Nc][K]^T (+res), fp32 out ----------------
template <bool RES>
__global__ __launch_bounds__(256, 3) void gemm_f32(
    const unsigned short* __restrict__ A, const unsigned short* __restrict__ Bt,
    const float* __restrict__ res, float* __restrict__ C, int Nc, int K) {
  __shared__ __align__(16) unsigned short Asm[2 * 128 * 32];
  __shared__ __align__(16) unsigned short Bsm[2 * 128 * 32];
  int tid = threadIdx.x;
  int w = tid >> 6, l = tid & 63;
  int bm = blockIdx.y * 128, bn = blockIdx.x * 128;
  int wr = (w >> 1) * 64, wc = (w & 1) * 64;
  int c0 = l & 15, g = l >> 4;

  int sr = w * 32 + (l >> 2);
  int sc = ((l & 3) ^ ((sr >> 1) & 3)) * 8;
  const unsigned short* gA0 = A + (size_t)(bm + sr) * K + sc;
  const unsigned short* gA1 = A + (size_t)(bm + sr + 16) * K + sc;
  const unsigned short* gB0 = Bt + (size_t)(bn + sr) * K + sc;
  const unsigned short* gB1 = Bt + (size_t)(bn + sr + 16) * K + sc;
  int ls0 = (w * 32) * 32, ls1 = (w * 32 + 16) * 32;

  int aoff[4], boff[4];
#pragma unroll
  for (int m = 0; m < 4; m++) {
    int ra = wr + m * 16 + c0;
    aoff[m] = ra * 32 + (g ^ ((ra >> 1) & 3)) * 8;
    int rb = wc + m * 16 + c0;
    boff[m] = rb * 32 + (g ^ ((rb >> 1) & 3)) * 8;
  }

  f32x4 acc[4][4] = {};
  int nsteps = K / 32;
  glds16(gA0, &Asm[ls0]);
  glds16(gA1, &Asm[ls1]);
  glds16(gB0, &Bsm[ls0]);
  glds16(gB1, &Bsm[ls1]);
  __syncthreads();
  int buf = 0;
  for (int s = 0; s < nsteps; ++s) {
    int nb = buf ^ 1;
    if (s + 1 < nsteps) {
      int ko = (s + 1) * 32;
      glds16(gA0 + ko, &Asm[nb * 4096 + ls0]);
      glds16(gA1 + ko, &Asm[nb * 4096 + ls1]);
      glds16(gB0 + ko, &Bsm[nb * 4096 + ls0]);
      glds16(gB1 + ko, &Bsm[nb * 4096 + ls1]);
    }
    const unsigned short* As = &Asm[buf * 4096];
    const unsigned short* Bs = &Bsm[buf * 4096];
    short8 af[4], bf[4];
#pragma unroll
    for (int m = 0; m < 4; m++) af[m] = *(const short8*)&As[aoff[m]];
#pragma unroll
    for (int n = 0; n < 4; n++) bf[n] = *(const short8*)&Bs[boff[n]];
#pragma unroll
    for (int m = 0; m < 4; m++)
#pragma unroll
      for (int n = 0; n < 4; n++)
        acc[m][n] = __builtin_amdgcn_mfma_f32_16x16x32_bf16(af[m], bf[n], acc[m][n], 0, 0, 0);
    __syncthreads();
    buf = nb;
  }
  int gq = l >> 4;
#pragma unroll
  for (int m = 0; m < 4; m++) {
#pragma unroll
    for (int i = 0; i < 4; i++) {
      int row = bm + wr + m * 16 + gq * 4 + i;
#pragma unroll
      for (int n = 0; n < 4; n++) {
        int col = bn + wc + n * 16 + c0;
        float v = acc[m][n][i];
        if (RES) v += res[(size_t)row * Nc + col];
        C[(size_t)row * Nc + col] = v;
      }
    }
  }
}

// ---------------- fused FFN13: g = silu(A@W1t^T) * (A@W3t^T), bf16 out ----------------
__global__ __launch_bounds__(256, 3) void gemm_ffn13(
    const unsigned short* __restrict__ A, const unsigned short* __restrict__ B1t,
    const unsigned short* __restrict__ B3t, unsigned short* __restrict__ G,
    int Nc, int K) {
  __shared__ __align__(16) unsigned short Asm[2 * 128 * 32];
  __shared__ __align__(16) unsigned short B1sm[2 * 64 * 32];
  __shared__ __align__(16) unsigned short B3sm[2 * 64 * 32];
  int tid = threadIdx.x;
  int w = tid >> 6, l = tid & 63;
  int bm = blockIdx.y * 128, bn = blockIdx.x * 64;
  int wr = (w >> 1) * 64, wc = (w & 1) * 32;
  int c0 = l & 15, g = l >> 4;

  int sr = w * 32 + (l >> 2);
  int sb = w * 16 + (l >> 2);
  int sc  = ((l & 3) ^ ((sr >> 1) & 3)) * 8;
  int scb = ((l & 3) ^ ((sb >> 1) & 3)) * 8;
  const unsigned short* gA0 = A + (size_t)(bm + sr) * K + sc;
  const unsigned short* gA1 = A + (size_t)(bm + sr + 16) * K + sc;
  const unsigned short* gB1 = B1t + (size_t)(bn + sb) * K + scb;
  const unsigned short* gB3 = B3t + (size_t)(bn + sb) * K + scb;
  int ls0 = (w * 32) * 32, ls1 = (w * 32 + 16) * 32, lsb = (w * 16) * 32;

  int aoff[4], boff[2];
#pragma unroll
  for (int m = 0; m < 4; m++) {
    int ra = wr + m * 16 + c0;
    aoff[m] = ra * 32 + (g ^ ((ra >> 1) & 3)) * 8;
  }
#pragma unroll
  for (int n = 0; n < 2; n++) {
    int rb = wc + n * 16 + c0;
    boff[n] = rb * 32 + (g ^ ((rb >> 1) & 3)) * 8;
  }

  f32x4 a1[4][2] = {};
  f32x4 a3[4][2] = {};
  int nsteps = K / 32;
  glds16(gA0, &Asm[ls0]);
  glds16(gA1, &Asm[ls1]);
  glds16(gB1, &B1sm[lsb]);
  glds16(gB3, &B3sm[lsb]);
  __syncthreads();
  int buf = 0;
  for (int s = 0; s < nsteps; ++s) {
    int nb = buf ^ 1;
    if (s + 1 < nsteps) {
      int ko = (s + 1) * 32;
      glds16(gA0 + ko, &Asm[nb * 4096 + ls0]);
      glds16(gA1 + ko, &Asm[nb * 4096 + ls1]);
      glds16(gB1 + ko, &B1sm[nb * 2048 + lsb]);
      glds16(gB3 + ko, &B3sm[nb * 2048 + lsb]);
    }
    const unsigned short* As = &Asm[buf * 4096];
    const unsigned short* B1s = &B1sm[buf * 2048];
    const unsigned short* B3s = &B3sm[buf * 2048];
    short8 af[4], b1f[2], b3f[2];
#pragma unroll
    for (int m = 0; m < 4; m++) af[m] = *(const short8*)&As[aoff[m]];
#pragma unroll
    for (int n = 0; n < 2; n++) {
      b1f[n] = *(const short8*)&B1s[boff[n]];
      b3f[n] = *(const short8*)&B3s[boff[n]];
    }
#pragma unroll
    for (int m = 0; m < 4; m++)
#pragma unroll
      for (int n = 0; n < 2; n++) {
        a1[m][n] = __builtin_amdgcn_mfma_f32_16x16x32_bf16(af[m], b1f[n], a1[m][n], 0, 0, 0);
        a3[m][n] = __builtin_amdgcn_mfma_f32_16x16x32_bf16(af[m], b3f[n], a3[m][n], 0, 0, 0);
      }
    __syncthreads();
    buf = nb;
  }
  int gq = l >> 4;
#pragma unroll
  for (int m = 0; m < 4; m++) {
#pragma unroll
    for (int i = 0; i < 4; i++) {
      int row = bm + wr + m * 16 + gq * 4 + i;
#pragma unroll
      for (int n = 0; n < 2; n++) {
        int col = bn + wc + n * 16 + c0;
        float x1 = a1[m][n][i], x3 = a3[m][n][i];
        float sg = x1 / (1.0f + __expf(-x1));
        G[(size_t)row * Nc + col] = f2bf(sg * x3);
      }
    }
  }
}

// ---------------- qkv fp32 -> rope'd bf16 q (pre-scaled by 1/8) / k + transposed v ------
__global__ void prep_qkv(const float* __restrict__ qkv, const float* __restrict__ cosb,
                         const float* __restrict__ sinb, unsigned short* __restrict__ qb,
                         unsigned short* __restrict__ kb, unsigned short* __restrict__ vtb) {
  int n = blockIdx.x, b = blockIdx.y;
  int t = threadIdx.x;
  const float* row = qkv + ((size_t)b * NN + n) * 1536;
#pragma unroll
  for (int p = t; p < 512; p += 256) {
    int head = p >> 5, j = p & 31;
    float xr = row[head * 64 + 2 * j], xi = row[head * 64 + 2 * j + 1];
    float c = cosb[n * 32 + j], s = sinb[n * 32 + j];
    size_t o = (((size_t)(b * NH + head)) * NN + n) * 64 + 2 * j;
    qb[o] = f2bf((xr * c - xi * s) * 0.125f);
    qb[o + 1] = f2bf((xr * s + xi * c) * 0.125f);
  }
  if (t < 128) {
    int kvh = t >> 5, j = t & 31;
    float xr = row[1024 + kvh * 64 + 2 * j], xi = row[1024 + kvh * 64 + 2 * j + 1];
    float c = cosb[n * 32 + j], s = sinb[n * 32 + j];
    size_t o = (((size_t)(b * NKV + kvh)) * NN + n) * 64 + 2 * j;
    kb[o] = f2bf(xr * c - xi * s);
    kb[o + 1] = f2bf(xr * s + xi * c);
  }
  {
    int kvh = t >> 6, d = t & 63;
    float v = row[1280 + kvh * 64 + d];
    vtb[(((size_t)(b * NKV + kvh)) * 64 + d) * NN + n] = f2bf(v);
  }
}

// ---------------- flash attention v4: 32x32 MFMA, swapped QK^T, in-lane softmax ------
// 4 warps x 32 q-rows = 128 q/block. K,V^T tiles (64x64) glds-staged, XOR-swizzled
// (chunk ^= row&7), double-buffered, 1 barrier/tile. P built in-register via
// v_cvt_pk_bf16_f32 + v_permlane32_swap_b32 (no LDS P roundtrip).
__global__ __launch_bounds__(256, 3) void attn_k(
    const unsigned short* __restrict__ qg_, const unsigned short* __restrict__ kg_,
    const unsigned short* __restrict__ vg_, unsigned short* __restrict__ ob) {
  __shared__ __align__(16) unsigned short Ksm[2][64 * 64];
  __shared__ __align__(16) unsigned short Vsm[2][64 * 64];
  // complementary qb pairing across b for causal load balance
  int qb = (blockIdx.z == 0) ? (int)blockIdx.x : ((int)gridDim.x - 1 - (int)blockIdx.x);
  int h = blockIdx.y, b = blockIdx.z;
  int kvh = h & 3;  // jnp.tile semantics
  int tid = threadIdx.x, w = tid >> 6, l = tid & 63;
  int q5 = l & 31, hi = l >> 5;
  int qwbase = qb * 128 + w * 32;
  int qgl = qwbase + q5;

  const unsigned short* Kg = kg_ + ((size_t)(b * NKV + kvh)) * NN * 64;
  const unsigned short* Vg = vg_ + ((size_t)(b * NKV + kvh)) * 64 * NN;

  // Q B-fragments: lane holds Q[qgl][dstep*16 + hi*8 + j]
  short8 qf[4];
  {
    const unsigned short* qrow = qg_ + (((size_t)(b * NH + h)) * NN + qgl) * 64 + hi * 8;
#pragma unroll
    for (int d = 0; d < 4; d++) qf[d] = *(const short8*)(qrow + d * 16);
  }

  // staging: wave w covers rows [w*16, w*16+16), 2 glds calls each for K and V
  int srow = l >> 3;
  int schunk = (l & 7) ^ (srow & 7);  // inverse-swizzled source chunk
  const unsigned short* gK = Kg + (size_t)(w * 16 + srow) * 64 + schunk * 8;
  const unsigned short* gV = Vg + (size_t)(w * 16 + srow) * NN + schunk * 8;

  int nkt = qb * 2 + 2;
  int nkt_w = ((qwbase + 31) >> 6) + 1;

  f32x16 O0 = {}, O1 = {};
  float m_r = -1e30f, l_r = 0.0f;

  glds16(gK, &Ksm[0][w * 1024]);
  glds16(gK + 8 * 64, &Ksm[0][w * 1024 + 512]);
  glds16(gV, &Vsm[0][w * 1024]);
  glds16(gV + 8 * NN, &Vsm[0][w * 1024 + 512]);
  __syncthreads();

  int buf = 0;
  for (int kt = 0; kt < nkt; ++kt) {
    int n0 = kt * 64;
    if (kt + 1 < nkt) {
      int nb = buf ^ 1;
      glds16(gK + (size_t)(n0 + 64) * 64, &Ksm[nb][w * 1024]);
      glds16(gK + (size_t)(n0 + 64) * 64 + 8 * 64, &Ksm[nb][w * 1024 + 512]);
      glds16(gV + n0 + 64, &Vsm[nb][w * 1024]);
      glds16(gV + 8 * NN + n0 + 64, &Vsm[nb][w * 1024 + 512]);
    }
    if (kt < nkt_w) {
      const unsigned short* Ks = Ksm[buf];
      const unsigned short* Vs = Vsm[buf];
      // S^T = K @ Q^T : lane holds S[q=q5][k' = CROW(r,hi) + 32s]
      f32x16 S[2];
      __builtin_amdgcn_s_setprio(1);
#pragma unroll
      for (int s = 0; s < 2; s++) {
        f32x16 acc = {};
        int row = s * 32 + q5;
#pragma unroll
        for (int d = 0; d < 4; d++) {
          int ch = (2 * d + hi) ^ (row & 7);
          short8 kf = *(const short8*)&Ks[row * 64 + ch * 8];
          acc = __builtin_amdgcn_mfma_f32_32x32x16_bf16(kf, qf[d], acc, 0, 0, 0);
        }
        S[s] = acc;
      }
      __builtin_amdgcn_s_setprio(0);
      if (kt == nkt_w - 1) {  // only the diagonal tile needs masking
#pragma unroll
        for (int s = 0; s < 2; s++)
#pragma unroll
          for (int r = 0; r < 16; r++) {
            int kg = n0 + s * 32 + CROW(r, hi);
            S[s][r] = (kg > qgl) ? -1e30f : S[s][r];
          }
      }
      // in-lane softmax over 32 values + one cross-half exchange
      float t[16];
#pragma unroll
      for (int r = 0; r < 16; r++) t[r] = fmaxf(S[0][r], S[1][r]);
#pragma unroll
      for (int k = 8; k >= 1; k >>= 1)
#pragma unroll
        for (int r = 0; r < k; r++) t[r] = fmaxf(t[r], t[r + k]);
      float pm = fmaxf(t[0], __shfl_xor(t[0], 32));
      float mn = fmaxf(m_r, pm);
      float alpha = __expf(m_r - mn);
      m_r = mn;
#pragma unroll
      for (int s = 0; s < 2; s++)
#pragma unroll
        for (int r = 0; r < 16; r++) S[s][r] = __expf(S[s][r] - mn);
      float u[16];
#pragma unroll
      for (int r = 0; r < 16; r++) u[r] = S[0][r] + S[1][r];
#pragma unroll
      for (int k = 8; k >= 1; k >>= 1)
#pragma unroll
        for (int r = 0; r < k; r++) u[r] += u[r + k];
      l_r = l_r * alpha + (u[0] + __shfl_xor(u[0], 32));
      // broadcast alpha into O-row layout, rescale O
      float ab[16];
#pragma unroll
      for (int r = 0; r < 16; r++) ab[r] = __shfl(alpha, CROW(r, 0) + 4 * hi);
#pragma unroll
      for (int r = 0; r < 16; r++) { O0[r] *= ab[r]; O1[r] *= ab[r]; }
      // P -> bf16 A-fragments: cvt_pk pairs + permlane32_swap (T12)
      short8 paf[4];
#pragma unroll
      for (int ks = 0; ks < 4; ks++) {
        const int s = ks >> 1, e = ks & 1;
        unsigned a0, a1, b0, b1;
        asm("v_cvt_pk_bf16_f32 %0, %1, %2" : "=v"(a0) : "v"(S[s][8*e+0]), "v"(S[s][8*e+1]));
        asm("v_cvt_pk_bf16_f32 %0, %1, %2" : "=v"(a1) : "v"(S[s][8*e+2]), "v"(S[s][8*e+3]));
        asm("v_cvt_pk_bf16_f32 %0, %1, %2" : "=v"(b0) : "v"(S[s][8*e+4]), "v"(S[s][8*e+5]));
        asm("v_cvt_pk_bf16_f32 %0, %1, %2" : "=v"(b1) : "v"(S[s][8*e+6]), "v"(S[s][8*e+7]));
        asm("v_permlane32_swap_b32 %0, %1" : "+v"(a0), "+v"(b0));
        asm("v_permlane32_swap_b32 %0, %1" : "+v"(a1), "+v"(b1));
        union { unsigned u4[4]; short8 s8; } pk;
        pk.u4[0] = a0; pk.u4[1] = a1; pk.u4[2] = b0; pk.u4[3] = b1;
        paf[ks] = pk.s8;
      }
      // O += P @ V  (V^T tile: B-frag = VT[db*32+q5][ks*16+hi*8+j])
      __builtin_amdgcn_s_setprio(1);
#pragma unroll
      for (int ks = 0; ks < 4; ks++) {
        int row0 = q5, row1 = 32 + q5;
        short8 vf0 = *(const short8*)&Vs[row0 * 64 + (((2 * ks + hi) ^ (row0 & 7)) * 8)];
        short8 vf1 = *(const short8*)&Vs[row1 * 64 + (((2 * ks + hi) ^ (row1 & 7)) * 8)];
        O0 = __builtin_amdgcn_mfma_f32_32x32x16_bf16(paf[ks], vf0, O0, 0, 0, 0);
        O1 = __builtin_amdgcn_mfma_f32_32x32x16_bf16(paf[ks], vf1, O1, 0, 0, 0);
      }
      __builtin_amdgcn_s_setprio(0);
    }
    __syncthreads();
    buf ^= 1;
  }
  float linv = 1.0f / l_r;
  float lb[16];
#pragma unroll
  for (int r = 0; r < 16; r++) lb[r] = __shfl(linv, CROW(r, 0) + 4 * hi);
#pragma unroll
  for (int r = 0; r < 16; r++) {
    int orow = qwbase + CROW(r, hi);
    size_t base = ((size_t)b * NN + orow) * 1024 + h * 64 + q5;
    ob[base] = f2bf(O0[r] * lb[r]);
    ob[base + 32] = f2bf(O1[r] * lb[r]);
  }
}

// ---------------- launcher ----------------
extern "C" void kernel_launch(void* const* d_in, const int* in_sizes, int n_in,
                              void* d_out, int out_size, void* d_ws, size_t ws_size,
                              hipStream_t stream) {
  (void)in_sizes; (void)n_in; (void)out_size; (void)ws_size;
  const float* x    = (const float*)d_in[0];
  const float* w_an = (const float*)d_in[1];
  const float* w_fn = (const float*)d_in[2];
  const float* Wq   = (const float*)d_in[3];
  const float* Wkv  = (const float*)d_in[4];
  const float* Wo   = (const float*)d_in[5];
  const float* W1   = (const float*)d_in[6];
  const float* W2   = (const float*)d_in[7];
  const float* W3   = (const float*)d_in[8];
  const float* cosb = (const float*)d_in[9];
  const float* sinb = (const float*)d_in[10];
  float* out = (float*)d_out;

  char* ws = (char*)d_ws;
  size_t off = 0;
  auto take = [&](size_t bytes) {
    size_t r = off;
    off += (bytes + 255) & ~(size_t)255;
    return r;
  };
  unsigned short* WqkvT = (unsigned short*)(ws + take((size_t)1536 * 1024 * 2));
  unsigned short* WoT   = (unsigned short*)(ws + take((size_t)1024 * 1024 * 2));
  unsigned short* W1T   = (unsigned short*)(ws + take((size_t)2688 * 1024 * 2));
  unsigned short* W3T   = (unsigned short*)(ws + take((size_t)2688 * 1024 * 2));
  unsigned short* W2T   = (unsigned short*)(ws + take((size_t)2688 * 1024 * 2));
  unsigned short* hA    = (unsigned short*)(ws + take((size_t)MM * DIM * 2));  // reused as h2
  char* qkv_region = ws + take((size_t)MM * 1536 * 4);  // reused as g
  float* qkv = (float*)qkv_region;
  unsigned short* gbuf = (unsigned short*)qkv_region;
  unsigned short* qbuf = (unsigned short*)(ws + take((size_t)MM * DIM * 2));
  unsigned short* kbuf = (unsigned short*)(ws + take((size_t)BB * NKV * NN * HD * 2));
  unsigned short* vtb  = (unsigned short*)(ws + take((size_t)BB * NKV * NN * HD * 2));
  unsigned short* obuf = (unsigned short*)(ws + take((size_t)MM * DIM * 2));
  float* x2 = (float*)(ws + take((size_t)MM * DIM * 4));

  transpose_k<<<dim3(1024 / 32, 1024 / 32), 256, 0, stream>>>(Wq, WqkvT, 1024, 1024);
  transpose_k<<<dim3(512 / 32, 1024 / 32), 256, 0, stream>>>(Wkv, WqkvT + (size_t)1024 * 1024, 1024, 512);
  transpose_k<<<dim3(1024 / 32, 1024 / 32), 256, 0, stream>>>(Wo, WoT, 1024, 1024);
  transpose_k<<<dim3(2688 / 32, 1024 / 32), 256, 0, stream>>>(W1, W1T, 1024, 2688);
  transpose_k<<<dim3(2688 / 32, 1024 / 32), 256, 0, stream>>>(W3, W3T, 1024, 2688);
  transpose_k<<<dim3(1024 / 32, 2688 / 32), 256, 0, stream>>>(W2, W2T, 2688, 1024);

  rmsnorm_k<<<MM, 256, 0, stream>>>(x, w_an, hA);
  gemm_f32<false><<<dim3(1536 / 128, MM / 128), 256, 0, stream>>>(hA, WqkvT, nullptr, qkv, 1536, 1024);
  prep_qkv<<<dim3(NN, BB), 256, 0, stream>>>(qkv, cosb, sinb, qbuf, kbuf, vtb);
  attn_k<<<dim3(NN / 128, NH, BB), 256, 0, stream>>>(qbuf, kbuf, vtb, obuf);
  gemm_f32<true><<<dim3(1024 / 128, MM / 128), 256, 0, stream>>>(obuf, WoT, x, x2, 1024, 1024);
  rmsnorm_k<<<MM, 256, 0, stream>>>(x2, w_fn, hA);
  gemm_ffn13<<<dim3(INTER / 64, MM / 128), 256, 0, stream>>>(hA, W1T, W3T, gbuf, INTER, 1024);
  gemm_f32<true><<<dim3(1024 / 128, MM / 128), 256, 0, stream>>>(gbuf, W2T, x2, out, 1024, 2688);
}